// Round 1
// baseline (47.024 us; speedup 1.0000x reference)
//
#include <hip/hip_runtime.h>
#include <hip/hip_bf16.h>

#define B_TOT 16384
#define MTILE 32

typedef __bf16 bf16x8 __attribute__((ext_vector_type(8)));
typedef float  f32x4  __attribute__((ext_vector_type(4)));

// ---- workspace layout (bytes) ----
// wp0: [17 ksteps][8 nblk][64 lanes][8 bf16]   (W_ih0|W_hh0 concat, K=544 padded)
// wp1: [ 8 ksteps][8 nblk][64 lanes][8 bf16]   (W_ih1|W_hh1 concat, K=256)
// wph: [ 4 ksteps][1 nblk][64 lanes][8 bf16]   (W_cls|W_act padded to N=16)
#define NG0 (17*8*64)
#define NG1 (8*8*64)
#define NGH (4*64)
#define WP0_OFF  0
#define WP1_OFF  (NG0*16)
#define WPH_OFF  (WP1_OFF + NG1*16)
#define BIAS0_OFF (WPH_OFF + NGH*16)
#define BIAS1_OFF (BIAS0_OFF + 512)
#define BIASH_OFF (BIAS1_OFF + 512)

__global__ __launch_bounds__(256) void prepack_kernel(
    const float* __restrict__ Wih0, const float* __restrict__ Whh0,
    const float* __restrict__ Wih1, const float* __restrict__ Whh1,
    const float* __restrict__ Wcls, const float* __restrict__ Wact,
    const float* __restrict__ bih0, const float* __restrict__ bhh0,
    const float* __restrict__ bih1, const float* __restrict__ bhh1,
    const float* __restrict__ bcls, const float* __restrict__ bact,
    char* __restrict__ ws)
{
    int idx = blockIdx.x * 256 + threadIdx.x;
    __bf16* wp0 = (__bf16*)(ws + WP0_OFF);
    __bf16* wp1 = (__bf16*)(ws + WP1_OFF);
    __bf16* wph = (__bf16*)(ws + WPH_OFF);
    float* bias0 = (float*)(ws + BIAS0_OFF);
    float* bias1 = (float*)(ws + BIAS1_OFF);
    float* biash = (float*)(ws + BIASH_OFF);

    if (idx < NG0) {
        // B-fragment: lane holds W[n = nb*16+(lane&15)][k = s*32+(lane>>4)*8 + j]
        int lane = idx & 63, g = idx >> 6, s = g >> 3, nb = g & 7;
        int n = nb * 16 + (lane & 15);
        int kb = s * 32 + (lane >> 4) * 8;
        bf16x8 v;
        #pragma unroll
        for (int j = 0; j < 8; ++j) {
            int k = kb + j;
            float x = 0.f;
            if (k < 400)      x = Wih0[n * 400 + k];
            else if (k < 528) x = Whh0[n * 128 + (k - 400)];
            v[j] = (__bf16)x;
        }
        *(bf16x8*)(wp0 + (size_t)idx * 8) = v;
    } else if (idx < NG0 + NG1) {
        int i2 = idx - NG0;
        int lane = i2 & 63, g = i2 >> 6, s = g >> 3, nb = g & 7;
        int n = nb * 16 + (lane & 15);
        int kb = s * 32 + (lane >> 4) * 8;
        bf16x8 v;
        #pragma unroll
        for (int j = 0; j < 8; ++j) {
            int k = kb + j;
            float x = (k < 128) ? Wih1[n * 128 + k] : Whh1[n * 128 + (k - 128)];
            v[j] = (__bf16)x;
        }
        *(bf16x8*)(wp1 + (size_t)i2 * 8) = v;
    } else if (idx < NG0 + NG1 + NGH) {
        int i3 = idx - NG0 - NG1;
        int lane = i3 & 63, s = i3 >> 6;
        int n = lane & 15;
        int kb = s * 32 + (lane >> 4) * 8;
        bf16x8 v;
        #pragma unroll
        for (int j = 0; j < 8; ++j) {
            int k = kb + j;
            float x = 0.f;
            if (n < 10)      x = Wcls[n * 128 + k];
            else if (n < 12) x = Wact[(n - 10) * 128 + k];
            v[j] = (__bf16)x;
        }
        *(bf16x8*)(wph + (size_t)i3 * 8) = v;
    } else {
        int i4 = idx - NG0 - NG1 - NGH;
        if (i4 < 128) bias0[i4] = bih0[i4] + bhh0[i4];
        else if (i4 < 256) { int i = i4 - 128; bias1[i] = bih1[i] + bhh1[i]; }
        else if (i4 < 272) {
            int i = i4 - 256;
            biash[i] = (i < 10) ? bcls[i] : ((i < 12) ? bact[i - 10] : 0.f);
        }
    }
}

// LDS layout (bf16 elems):
//   xl  [32][552]  : crop X (cols 0..399) | h0[0] (cols 400..527) | zero pad (528..551)
//   hb  [32][264]  : h1 (cols 0..127) | h0[1] (cols 128..255)
//   h2b [32][136]  : h2 (aliases xl region, used after xl is dead)
// strides*2B mod 128 = 80 / 16 / 16  -> <=2-way LDS bank aliasing on ds_read_b128
#define XSTR 552
#define HSTR 264
#define H2STR 136

__global__ __launch_bounds__(256) void mnist_rnn_main(
    const float* __restrict__ image, const int* __restrict__ center,
    const float* __restrict__ h0, const char* __restrict__ ws,
    float* __restrict__ out)
{
    const bf16x8* wp0 = (const bf16x8*)(ws + WP0_OFF);
    const bf16x8* wp1 = (const bf16x8*)(ws + WP1_OFF);
    const bf16x8* wph = (const bf16x8*)(ws + WPH_OFF);
    const float* bias0 = (const float*)(ws + BIAS0_OFF);
    const float* bias1 = (const float*)(ws + BIAS1_OFF);
    const float* biash = (const float*)(ws + BIASH_OFF);

    __shared__ __align__(16) __bf16 smem[MTILE * XSTR + MTILE * HSTR];
    __bf16* xl  = smem;                 // [32][552]
    __bf16* hb  = smem + MTILE * XSTR;  // [32][264]
    __bf16* h2b = smem;                 // [32][136] alias of xl

    const int t  = threadIdx.x;
    const int m0 = blockIdx.x * MTILE;

    // ---- stage h0 (both layers) as bf16 ----
    for (int i = t; i < MTILE * 128; i += 256) {
        int m = i >> 7, kk = i & 127;
        float v0 = h0[(size_t)(m0 + m) * 128 + kk];
        float v1 = h0[(size_t)B_TOT * 128 + (size_t)(m0 + m) * 128 + kk];
        xl[m * XSTR + 400 + kk] = (__bf16)v0;
        hb[m * HSTR + 128 + kk] = (__bf16)v1;
    }
    // ---- zero K-pad cols 528..551 ----
    for (int i = t; i < MTILE * 24; i += 256) {
        int m = i / 24, c = i - m * 24;
        xl[m * XSTR + 528 + c] = (__bf16)0.f;
    }
    // ---- crop gather: 8 threads per sample ----
    {
        int m = t >> 3, sub = t & 7;
        int cx = center[(m0 + m) * 2 + 0];
        int cy = center[(m0 + m) * 2 + 1];
        const float* img = image + (size_t)(m0 + m) * 784;
        for (int r = sub; r < 20; r += 8) {
            int iy = cy - 20 + r;                 // image row
            bool yok = ((unsigned)iy) < 28u;
            const float* row = img + iy * 28;
            int ix0 = cx - 20;
            #pragma unroll
            for (int c = 0; c < 20; ++c) {
                int ix = ix0 + c;
                float v = (yok && ((unsigned)ix) < 28u) ? row[ix] : 0.f;
                xl[m * XSTR + r * 20 + c] = (__bf16)v;
            }
        }
    }
    __syncthreads();

    const int lane = t & 63;
    const int w = t >> 6;
    const int wm = w >> 1, wn = w & 1;      // 2x2 wave grid: 16 rows x 64 cols each
    const int qr = lane >> 4, lr = lane & 15;
    const int mrow = wm * 16 + lr;          // A-fragment row (lane&15 = row)

    float* outh1 = out + (size_t)B_TOT * 12;
    float* outh2 = out + (size_t)B_TOT * 140;

    // ================= GEMM0: h1 = tanh([X|h0_0] @ [Wih0|Whh0]^T + b) =================
    f32x4 acc0[4] = {};
    {
        const __bf16* aX = xl + mrow * XSTR + qr * 8;
        #pragma unroll
        for (int s = 0; s < 17; ++s) {
            bf16x8 a = *(const bf16x8*)(aX + s * 32);
            #pragma unroll
            for (int f = 0; f < 4; ++f) {
                bf16x8 b = wp0[(size_t)(s * 8 + wn * 4 + f) * 64 + lane];
                acc0[f] = __builtin_amdgcn_mfma_f32_16x16x32_bf16(a, b, acc0[f], 0, 0, 0);
            }
        }
    }
    #pragma unroll
    for (int f = 0; f < 4; ++f) {
        int n = wn * 64 + f * 16 + lr;      // D: col = lane&15
        float bv = bias0[n];
        #pragma unroll
        for (int r = 0; r < 4; ++r) {       // D: row = (lane>>4)*4 + r
            int mloc = wm * 16 + qr * 4 + r;
            float hv = tanhf(acc0[f][r] + bv);
            outh1[(size_t)(m0 + mloc) * 128 + n] = hv;
            hb[mloc * HSTR + n] = (__bf16)hv;
        }
    }
    __syncthreads();

    // ================= GEMM1: h2 = tanh([h1|h0_1] @ [Wih1|Whh1]^T + b) =================
    f32x4 acc1[4] = {};
    {
        const __bf16* aH = hb + mrow * HSTR + qr * 8;
        #pragma unroll
        for (int s = 0; s < 8; ++s) {
            bf16x8 a = *(const bf16x8*)(aH + s * 32);
            #pragma unroll
            for (int f = 0; f < 4; ++f) {
                bf16x8 b = wp1[(size_t)(s * 8 + wn * 4 + f) * 64 + lane];
                acc1[f] = __builtin_amdgcn_mfma_f32_16x16x32_bf16(a, b, acc1[f], 0, 0, 0);
            }
        }
    }
    #pragma unroll
    for (int f = 0; f < 4; ++f) {
        int n = wn * 64 + f * 16 + lr;
        float bv = bias1[n];
        #pragma unroll
        for (int r = 0; r < 4; ++r) {
            int mloc = wm * 16 + qr * 4 + r;
            float hv = tanhf(acc1[f][r] + bv);
            outh2[(size_t)(m0 + mloc) * 128 + n] = hv;
            h2b[mloc * H2STR + n] = (__bf16)hv;
        }
    }
    __syncthreads();

    // ================= heads: [cls|act] = h2 @ [Wcls|Wact]^T + b (N padded to 16) ======
    if (wn == 0) {
        f32x4 acc2 = {};
        const __bf16* aH2 = h2b + mrow * H2STR + qr * 8;
        #pragma unroll
        for (int s = 0; s < 4; ++s) {
            bf16x8 a = *(const bf16x8*)(aH2 + s * 32);
            bf16x8 b = wph[(size_t)s * 64 + lane];
            acc2 = __builtin_amdgcn_mfma_f32_16x16x32_bf16(a, b, acc2, 0, 0, 0);
        }
        int n = lr;
        float bh = biash[n];
        #pragma unroll
        for (int r = 0; r < 4; ++r) {
            int mg = m0 + wm * 16 + qr * 4 + r;
            float v = acc2[r] + bh;
            if (n < 10)      out[(size_t)mg * 10 + n] = v;
            else if (n < 12) out[(size_t)B_TOT * 10 + (size_t)mg * 2 + (n - 10)] = v;
        }
    }
}

extern "C" void kernel_launch(void* const* d_in, const int* in_sizes, int n_in,
                              void* d_out, int out_size, void* d_ws, size_t ws_size,
                              hipStream_t stream) {
    const float* image = (const float*)d_in[0];
    const int*   center = (const int*)d_in[1];
    const float* h0   = (const float*)d_in[2];
    const float* Wih0 = (const float*)d_in[3];
    const float* bih0 = (const float*)d_in[4];
    const float* Whh0 = (const float*)d_in[5];
    const float* bhh0 = (const float*)d_in[6];
    const float* Wih1 = (const float*)d_in[7];
    const float* bih1 = (const float*)d_in[8];
    const float* Whh1 = (const float*)d_in[9];
    const float* bhh1 = (const float*)d_in[10];
    const float* Wcls = (const float*)d_in[11];
    const float* bcls = (const float*)d_in[12];
    const float* Wact = (const float*)d_in[13];
    const float* bact = (const float*)d_in[14];

    prepack_kernel<<<53, 256, 0, stream>>>(Wih0, Whh0, Wih1, Whh1, Wcls, Wact,
                                           bih0, bhh0, bih1, bhh1, bcls, bact,
                                           (char*)d_ws);
    mnist_rnn_main<<<B_TOT / MTILE, 256, 0, stream>>>(
        image, center, h0, (const char*)d_ws, (float*)d_out);
}

// Round 2
// 43.442 us; speedup vs baseline: 1.0824x; 1.0824x over previous
//
#include <hip/hip_runtime.h>
#include <hip/hip_bf16.h>

#define B_TOT 16384
#define MTILE 16

typedef __bf16 bf16x8 __attribute__((ext_vector_type(8)));
typedef __bf16 bf16x4 __attribute__((ext_vector_type(4)));
typedef float  f32x4  __attribute__((ext_vector_type(4)));

// ---- workspace layout (bytes) ----
// wp0: [17 ksteps][8 nblk][64 lanes][8 bf16]   (W_ih0|W_hh0 concat, K=544 padded)
// wp1: [ 8 ksteps][8 nblk][64 lanes][8 bf16]   (W_ih1|W_hh1 concat, K=256)
// wph: [ 4 ksteps][1 nblk][64 lanes][8 bf16]   (W_cls|W_act padded to N=16)
#define NG0 (17*8*64)
#define NG1 (8*8*64)
#define NGH (4*64)
#define WP0_OFF  0
#define WP1_OFF  (NG0*16)
#define WPH_OFF  (WP1_OFF + NG1*16)
#define BIAS0_OFF (WPH_OFF + NGH*16)
#define BIAS1_OFF (BIAS0_OFF + 512)
#define BIASH_OFF (BIAS1_OFF + 512)

__global__ __launch_bounds__(256) void prepack_kernel(
    const float* __restrict__ Wih0, const float* __restrict__ Whh0,
    const float* __restrict__ Wih1, const float* __restrict__ Whh1,
    const float* __restrict__ Wcls, const float* __restrict__ Wact,
    const float* __restrict__ bih0, const float* __restrict__ bhh0,
    const float* __restrict__ bih1, const float* __restrict__ bhh1,
    const float* __restrict__ bcls, const float* __restrict__ bact,
    char* __restrict__ ws)
{
    int idx = blockIdx.x * 256 + threadIdx.x;
    __bf16* wp0 = (__bf16*)(ws + WP0_OFF);
    __bf16* wp1 = (__bf16*)(ws + WP1_OFF);
    __bf16* wph = (__bf16*)(ws + WPH_OFF);
    float* bias0 = (float*)(ws + BIAS0_OFF);
    float* bias1 = (float*)(ws + BIAS1_OFF);
    float* biash = (float*)(ws + BIASH_OFF);

    if (idx < NG0) {
        // B-fragment: lane holds W[n = nb*16+(lane&15)][k = s*32+(lane>>4)*8 + j]
        int lane = idx & 63, g = idx >> 6, s = g >> 3, nb = g & 7;
        int n = nb * 16 + (lane & 15);
        int kb = s * 32 + (lane >> 4) * 8;
        bf16x8 v;
        #pragma unroll
        for (int j = 0; j < 8; ++j) {
            int k = kb + j;
            float x = 0.f;
            if (k < 400)      x = Wih0[n * 400 + k];
            else if (k < 528) x = Whh0[n * 128 + (k - 400)];
            v[j] = (__bf16)x;
        }
        *(bf16x8*)(wp0 + (size_t)idx * 8) = v;
    } else if (idx < NG0 + NG1) {
        int i2 = idx - NG0;
        int lane = i2 & 63, g = i2 >> 6, s = g >> 3, nb = g & 7;
        int n = nb * 16 + (lane & 15);
        int kb = s * 32 + (lane >> 4) * 8;
        bf16x8 v;
        #pragma unroll
        for (int j = 0; j < 8; ++j) {
            int k = kb + j;
            float x = (k < 128) ? Wih1[n * 128 + k] : Whh1[n * 128 + (k - 128)];
            v[j] = (__bf16)x;
        }
        *(bf16x8*)(wp1 + (size_t)i2 * 8) = v;
    } else if (idx < NG0 + NG1 + NGH) {
        int i3 = idx - NG0 - NG1;
        int lane = i3 & 63, s = i3 >> 6;
        int n = lane & 15;
        int kb = s * 32 + (lane >> 4) * 8;
        bf16x8 v;
        #pragma unroll
        for (int j = 0; j < 8; ++j) {
            int k = kb + j;
            float x = 0.f;
            if (n < 10)      x = Wcls[n * 128 + k];
            else if (n < 12) x = Wact[(n - 10) * 128 + k];
            v[j] = (__bf16)x;
        }
        *(bf16x8*)(wph + (size_t)i3 * 8) = v;
    } else {
        int i4 = idx - NG0 - NG1 - NGH;
        if (i4 < 128) bias0[i4] = bih0[i4] + bhh0[i4];
        else if (i4 < 256) { int i = i4 - 128; bias1[i] = bih1[i] + bhh1[i]; }
        else if (i4 < 272) {
            int i = i4 - 256;
            biash[i] = (i < 10) ? bcls[i] : ((i < 12) ? bact[i - 10] : 0.f);
        }
    }
}

// LDS layout (bf16 elems), MTILE=16:
//   xl  [16][552]  : crop X (0..399) | h0[0] (400..527) | zero pad (528..551)
//   hb  [16][264]  : h1 (0..127) | h0[1] (128..255)
//   h2b [16][136]  : h2 (aliases xl, used after xl dead)
// ds_read_b128 A-fragments: each 16B bank-group gets exactly 8 lanes -> even spread.
#define XSTR 552
#define HSTR 264
#define H2STR 136

__global__ __launch_bounds__(256) void mnist_rnn_main(
    const float* __restrict__ image, const int* __restrict__ center,
    const float* __restrict__ h0, const char* __restrict__ ws,
    float* __restrict__ out)
{
    const bf16x8* wp0 = (const bf16x8*)(ws + WP0_OFF);
    const bf16x8* wp1 = (const bf16x8*)(ws + WP1_OFF);
    const bf16x8* wph = (const bf16x8*)(ws + WPH_OFF);
    const float* bias0 = (const float*)(ws + BIAS0_OFF);
    const float* bias1 = (const float*)(ws + BIAS1_OFF);
    const float* biash = (const float*)(ws + BIASH_OFF);

    __shared__ __align__(16) __bf16 smem[MTILE * XSTR + MTILE * HSTR];
    __bf16* xl  = smem;                 // [16][552]
    __bf16* hb  = smem + MTILE * XSTR;  // [16][264]
    __bf16* h2b = smem;                 // [16][136] alias of xl

    const int t  = threadIdx.x;
    const int m0 = blockIdx.x * MTILE;

    // ---- stage h0 (both layers), float4 loads + bf16x4 LDS stores ----
    #pragma unroll
    for (int it = 0; it < 2; ++it) {
        int i = t + it * 256;                 // 512 tasks = 16 rows x 32 float4
        int m = i >> 5, k4 = (i & 31) * 4;
        const float4 v0 = *(const float4*)(h0 + (size_t)(m0 + m) * 128 + k4);
        const float4 v1 = *(const float4*)(h0 + (size_t)B_TOT * 128 + (size_t)(m0 + m) * 128 + k4);
        bf16x4 b0, b1;
        b0[0] = (__bf16)v0.x; b0[1] = (__bf16)v0.y; b0[2] = (__bf16)v0.z; b0[3] = (__bf16)v0.w;
        b1[0] = (__bf16)v1.x; b1[1] = (__bf16)v1.y; b1[2] = (__bf16)v1.z; b1[3] = (__bf16)v1.w;
        *(bf16x4*)(xl + m * XSTR + 400 + k4) = b0;
        *(bf16x4*)(hb + m * HSTR + 128 + k4) = b1;
    }
    // ---- zero K-pad cols 528..551 (16 rows x 24 cols = 192 u32 pairs) ----
    if (t < 192) {
        int m = t / 12, c = (t - m * 12) * 2;
        *(unsigned int*)(xl + m * XSTR + 528 + c) = 0u;
    }
    // ---- crop gather: 16 threads per sample, packed-pair LDS stores ----
    {
        int m = t >> 4, sub = t & 15;
        int cx = center[(m0 + m) * 2 + 0];
        int cy = center[(m0 + m) * 2 + 1];
        const float* img = image + (size_t)(m0 + m) * 784;
        for (int r = sub; r < 20; r += 16) {
            int iy = cy - 20 + r;
            bool yok = ((unsigned)iy) < 28u;
            const float* row = img + iy * 28;
            int ix0 = cx - 20;
            __bf16* dst = xl + m * XSTR + r * 20;
            #pragma unroll
            for (int c = 0; c < 20; c += 2) {
                int ix = ix0 + c;
                float va = (yok && ((unsigned)ix) < 28u) ? row[ix] : 0.f;
                float vb = (yok && ((unsigned)(ix + 1)) < 28u) ? row[ix + 1] : 0.f;
                union { __bf16 b[2]; unsigned int u; } p;
                p.b[0] = (__bf16)va; p.b[1] = (__bf16)vb;
                *(unsigned int*)(dst + c) = p.u;
            }
        }
    }
    __syncthreads();

    const int lane = t & 63;
    const int wn = t >> 6;                  // 4 waves along N: cols wn*32..wn*32+31
    const int qr = lane >> 4, lr = lane & 15;

    float* outh1 = out + (size_t)B_TOT * 12;
    float* outh2 = out + (size_t)B_TOT * 140;

    // ================= GEMM0: h1 = tanh([X|h0_0] @ [Wih0|Whh0]^T + b) =================
    f32x4 acc0[2] = {};
    {
        const __bf16* aX = xl + lr * XSTR + qr * 8;
        #pragma unroll
        for (int s = 0; s < 17; ++s) {
            bf16x8 a = *(const bf16x8*)(aX + s * 32);
            #pragma unroll
            for (int f = 0; f < 2; ++f) {
                bf16x8 b = wp0[(size_t)(s * 8 + wn * 2 + f) * 64 + lane];
                acc0[f] = __builtin_amdgcn_mfma_f32_16x16x32_bf16(a, b, acc0[f], 0, 0, 0);
            }
        }
    }
    #pragma unroll
    for (int f = 0; f < 2; ++f) {
        int n = wn * 32 + f * 16 + lr;      // D: col = lane&15
        float bv = bias0[n];
        #pragma unroll
        for (int r = 0; r < 4; ++r) {       // D: row = (lane>>4)*4 + r
            int mloc = qr * 4 + r;
            float hv = tanhf(acc0[f][r] + bv);
            outh1[(size_t)(m0 + mloc) * 128 + n] = hv;
            hb[mloc * HSTR + n] = (__bf16)hv;
        }
    }
    __syncthreads();

    // ================= GEMM1: h2 = tanh([h1|h0_1] @ [Wih1|Whh1]^T + b) =================
    f32x4 acc1[2] = {};
    {
        const __bf16* aH = hb + lr * HSTR + qr * 8;
        #pragma unroll
        for (int s = 0; s < 8; ++s) {
            bf16x8 a = *(const bf16x8*)(aH + s * 32);
            #pragma unroll
            for (int f = 0; f < 2; ++f) {
                bf16x8 b = wp1[(size_t)(s * 8 + wn * 2 + f) * 64 + lane];
                acc1[f] = __builtin_amdgcn_mfma_f32_16x16x32_bf16(a, b, acc1[f], 0, 0, 0);
            }
        }
    }
    #pragma unroll
    for (int f = 0; f < 2; ++f) {
        int n = wn * 32 + f * 16 + lr;
        float bv = bias1[n];
        #pragma unroll
        for (int r = 0; r < 4; ++r) {
            int mloc = qr * 4 + r;
            float hv = tanhf(acc1[f][r] + bv);
            outh2[(size_t)(m0 + mloc) * 128 + n] = hv;
            h2b[mloc * H2STR + n] = (__bf16)hv;
        }
    }
    __syncthreads();

    // ================= heads: [cls|act] = h2 @ [Wcls|Wact]^T + b (N padded to 16) ======
    if (wn == 0) {
        f32x4 acc2 = {};
        const __bf16* aH2 = h2b + lr * H2STR + qr * 8;
        #pragma unroll
        for (int s = 0; s < 4; ++s) {
            bf16x8 a = *(const bf16x8*)(aH2 + s * 32);
            bf16x8 b = wph[(size_t)s * 64 + lane];
            acc2 = __builtin_amdgcn_mfma_f32_16x16x32_bf16(a, b, acc2, 0, 0, 0);
        }
        int n = lr;
        float bh = biash[n];
        #pragma unroll
        for (int r = 0; r < 4; ++r) {
            int mg = m0 + qr * 4 + r;
            float v = acc2[r] + bh;
            if (n < 10)      out[(size_t)mg * 10 + n] = v;
            else if (n < 12) out[(size_t)B_TOT * 10 + (size_t)mg * 2 + (n - 10)] = v;
        }
    }
}

extern "C" void kernel_launch(void* const* d_in, const int* in_sizes, int n_in,
                              void* d_out, int out_size, void* d_ws, size_t ws_size,
                              hipStream_t stream) {
    const float* image = (const float*)d_in[0];
    const int*   center = (const int*)d_in[1];
    const float* h0   = (const float*)d_in[2];
    const float* Wih0 = (const float*)d_in[3];
    const float* bih0 = (const float*)d_in[4];
    const float* Whh0 = (const float*)d_in[5];
    const float* bhh0 = (const float*)d_in[6];
    const float* Wih1 = (const float*)d_in[7];
    const float* bih1 = (const float*)d_in[8];
    const float* Whh1 = (const float*)d_in[9];
    const float* bhh1 = (const float*)d_in[10];
    const float* Wcls = (const float*)d_in[11];
    const float* bcls = (const float*)d_in[12];
    const float* Wact = (const float*)d_in[13];
    const float* bact = (const float*)d_in[14];

    prepack_kernel<<<53, 256, 0, stream>>>(Wih0, Whh0, Wih1, Whh1, Wcls, Wact,
                                           bih0, bhh0, bih1, bhh1, bcls, bact,
                                           (char*)d_ws);
    mnist_rnn_main<<<B_TOT / MTILE, 256, 0, stream>>>(
        image, center, h0, (const char*)d_ws, (float*)d_out);
}

// Round 3
// 41.807 us; speedup vs baseline: 1.1248x; 1.0391x over previous
//
#include <hip/hip_runtime.h>
#include <hip/hip_bf16.h>

#define B_TOT 16384
#define MTILE 16

typedef __bf16 bf16x8 __attribute__((ext_vector_type(8)));
typedef __bf16 bf16x4 __attribute__((ext_vector_type(4)));
typedef float  f32x4  __attribute__((ext_vector_type(4)));

// ---- workspace layout (bytes) ----
// wp0: [17 ksteps][8 nblk][64 lanes][8 bf16]   (W_ih0|W_hh0 concat, K=544 padded)
// wp1: [ 8 ksteps][8 nblk][64 lanes][8 bf16]   (W_ih1|W_hh1 concat, K=256)
// wph: [ 4 ksteps][1 nblk][64 lanes][8 bf16]   (W_cls|W_act padded to N=16)
#define NG0 (17*8*64)
#define NG1 (8*8*64)
#define NGH (4*64)
#define WP0_OFF  0
#define WP1_OFF  (NG0*16)
#define WPH_OFF  (WP1_OFF + NG1*16)
#define BIAS0_OFF (WPH_OFF + NGH*16)
#define BIAS1_OFF (BIAS0_OFF + 512)
#define BIASH_OFF (BIAS1_OFF + 512)

__global__ __launch_bounds__(256) void prepack_kernel(
    const float* __restrict__ Wih0, const float* __restrict__ Whh0,
    const float* __restrict__ Wih1, const float* __restrict__ Whh1,
    const float* __restrict__ Wcls, const float* __restrict__ Wact,
    const float* __restrict__ bih0, const float* __restrict__ bhh0,
    const float* __restrict__ bih1, const float* __restrict__ bhh1,
    const float* __restrict__ bcls, const float* __restrict__ bact,
    char* __restrict__ ws)
{
    int idx = blockIdx.x * 256 + threadIdx.x;
    __bf16* wp0 = (__bf16*)(ws + WP0_OFF);
    __bf16* wp1 = (__bf16*)(ws + WP1_OFF);
    __bf16* wph = (__bf16*)(ws + WPH_OFF);
    float* bias0 = (float*)(ws + BIAS0_OFF);
    float* bias1 = (float*)(ws + BIAS1_OFF);
    float* biash = (float*)(ws + BIASH_OFF);

    if (idx < NG0) {
        // B-fragment: lane holds W[n = nb*16+(lane&15)][k = s*32+(lane>>4)*8 + j]
        int lane = idx & 63, g = idx >> 6, s = g >> 3, nb = g & 7;
        int n = nb * 16 + (lane & 15);
        int kb = s * 32 + (lane >> 4) * 8;
        bf16x8 v;
        #pragma unroll
        for (int j = 0; j < 8; ++j) {
            int k = kb + j;
            float x = 0.f;
            if (k < 400)      x = Wih0[n * 400 + k];
            else if (k < 528) x = Whh0[n * 128 + (k - 400)];
            v[j] = (__bf16)x;
        }
        *(bf16x8*)(wp0 + (size_t)idx * 8) = v;
    } else if (idx < NG0 + NG1) {
        int i2 = idx - NG0;
        int lane = i2 & 63, g = i2 >> 6, s = g >> 3, nb = g & 7;
        int n = nb * 16 + (lane & 15);
        int kb = s * 32 + (lane >> 4) * 8;
        bf16x8 v;
        #pragma unroll
        for (int j = 0; j < 8; ++j) {
            int k = kb + j;
            float x = (k < 128) ? Wih1[n * 128 + k] : Whh1[n * 128 + (k - 128)];
            v[j] = (__bf16)x;
        }
        *(bf16x8*)(wp1 + (size_t)i2 * 8) = v;
    } else if (idx < NG0 + NG1 + NGH) {
        int i3 = idx - NG0 - NG1;
        int lane = i3 & 63, s = i3 >> 6;
        int n = lane & 15;
        int kb = s * 32 + (lane >> 4) * 8;
        bf16x8 v;
        #pragma unroll
        for (int j = 0; j < 8; ++j) {
            int k = kb + j;
            float x = 0.f;
            if (n < 10)      x = Wcls[n * 128 + k];
            else if (n < 12) x = Wact[(n - 10) * 128 + k];
            v[j] = (__bf16)x;
        }
        *(bf16x8*)(wph + (size_t)i3 * 8) = v;
    } else {
        int i4 = idx - NG0 - NG1 - NGH;
        if (i4 < 128) bias0[i4] = bih0[i4] + bhh0[i4];
        else if (i4 < 256) { int i = i4 - 128; bias1[i] = bih1[i] + bhh1[i]; }
        else if (i4 < 272) {
            int i = i4 - 256;
            biash[i] = (i < 10) ? bcls[i] : ((i < 12) ? bact[i - 10] : 0.f);
        }
    }
}

// LDS layout (bf16 elems), MTILE=16:
//   xl  [16][552]  : crop X (0..399) | h0[0] (400..527) | zero pad (528..551)
//   hb  [16][264]  : h1 (0..127) | h0[1] (128..255)
//   h2b [16][136]  : h2 (aliases xl, used after xl dead)
#define XSTR 552
#define HSTR 264
#define H2STR 136

__global__ __launch_bounds__(512, 8) void mnist_rnn_main(
    const float* __restrict__ image, const int* __restrict__ center,
    const float* __restrict__ h0, const char* __restrict__ ws,
    float* __restrict__ out)
{
    const bf16x8* wp0 = (const bf16x8*)(ws + WP0_OFF);
    const bf16x8* wp1 = (const bf16x8*)(ws + WP1_OFF);
    const bf16x8* wph = (const bf16x8*)(ws + WPH_OFF);
    const float* bias0 = (const float*)(ws + BIAS0_OFF);
    const float* bias1 = (const float*)(ws + BIAS1_OFF);
    const float* biash = (const float*)(ws + BIASH_OFF);

    __shared__ __align__(16) __bf16 smem[MTILE * XSTR + MTILE * HSTR];
    __bf16* xl  = smem;                 // [16][552]
    __bf16* hb  = smem + MTILE * XSTR;  // [16][264]
    __bf16* h2b = smem;                 // [16][136] alias of xl

    const int t  = threadIdx.x;
    const int m0 = blockIdx.x * MTILE;
    const int lane = t & 63;
    const int wn = t >> 6;              // 8 waves along N: cols wn*16..wn*16+15
    const int qr = lane >> 4, lr = lane & 15;

    // ---- issue independent loads first: h0 (float4 pair) + weight prefetch ----
    const int hm = t >> 5, hk4 = (t & 31) * 4;   // 512 tasks = 16 rows x 32 float4
    const float4 v0 = *(const float4*)(h0 + (size_t)(m0 + hm) * 128 + hk4);
    const float4 v1 = *(const float4*)(h0 + (size_t)B_TOT * 128 + (size_t)(m0 + hm) * 128 + hk4);

    // prefetch first 4 GEMM0 B-fragments (independent of LDS)
    bf16x8 pb0 = wp0[(size_t)(0 * 8 + wn) * 64 + lane];
    bf16x8 pb1 = wp0[(size_t)(1 * 8 + wn) * 64 + lane];
    bf16x8 pb2 = wp0[(size_t)(2 * 8 + wn) * 64 + lane];
    bf16x8 pb3 = wp0[(size_t)(3 * 8 + wn) * 64 + lane];

    // ---- stage h0 to LDS ----
    {
        bf16x4 b0, b1;
        b0[0] = (__bf16)v0.x; b0[1] = (__bf16)v0.y; b0[2] = (__bf16)v0.z; b0[3] = (__bf16)v0.w;
        b1[0] = (__bf16)v1.x; b1[1] = (__bf16)v1.y; b1[2] = (__bf16)v1.z; b1[3] = (__bf16)v1.w;
        *(bf16x4*)(xl + hm * XSTR + 400 + hk4) = b0;
        *(bf16x4*)(hb + hm * HSTR + 128 + hk4) = b1;
    }
    // ---- zero K-pad cols 528..551 (16 rows x 12 u32 pairs) ----
    if (t < 192) {
        int m = t / 12, c = (t - m * 12) * 2;
        *(unsigned int*)(xl + m * XSTR + 528 + c) = 0u;
    }
    // ---- crop gather: 32 threads per sample, 1 row per thread ----
    {
        int m = t >> 5, sub = t & 31;
        if (sub < 20) {
            int cx = center[(m0 + m) * 2 + 0];
            int cy = center[(m0 + m) * 2 + 1];
            const float* img = image + (size_t)(m0 + m) * 784;
            int r = sub;
            int iy = cy - 20 + r;
            bool yok = ((unsigned)iy) < 28u;
            const float* row = img + iy * 28;
            int ix0 = cx - 20;
            __bf16* dst = xl + m * XSTR + r * 20;
            #pragma unroll
            for (int c = 0; c < 20; c += 2) {
                int ix = ix0 + c;
                float va = (yok && ((unsigned)ix) < 28u) ? row[ix] : 0.f;
                float vb = (yok && ((unsigned)(ix + 1)) < 28u) ? row[ix + 1] : 0.f;
                union { __bf16 b[2]; unsigned int u; } p;
                p.b[0] = (__bf16)va; p.b[1] = (__bf16)vb;
                *(unsigned int*)(dst + c) = p.u;
            }
        }
    }
    __syncthreads();

    float* outh1 = out + (size_t)B_TOT * 12;
    float* outh2 = out + (size_t)B_TOT * 140;

    // ================= GEMM0: h1 = tanh([X|h0_0] @ [Wih0|Whh0]^T + b) =================
    f32x4 acc0 = {};
    {
        const __bf16* aX = xl + lr * XSTR + qr * 8;
        bf16x8 a;
        a = *(const bf16x8*)(aX + 0 * 32);
        acc0 = __builtin_amdgcn_mfma_f32_16x16x32_bf16(a, pb0, acc0, 0, 0, 0);
        a = *(const bf16x8*)(aX + 1 * 32);
        acc0 = __builtin_amdgcn_mfma_f32_16x16x32_bf16(a, pb1, acc0, 0, 0, 0);
        a = *(const bf16x8*)(aX + 2 * 32);
        acc0 = __builtin_amdgcn_mfma_f32_16x16x32_bf16(a, pb2, acc0, 0, 0, 0);
        a = *(const bf16x8*)(aX + 3 * 32);
        acc0 = __builtin_amdgcn_mfma_f32_16x16x32_bf16(a, pb3, acc0, 0, 0, 0);
        #pragma unroll
        for (int s = 4; s < 17; ++s) {
            bf16x8 b = wp0[(size_t)(s * 8 + wn) * 64 + lane];
            a = *(const bf16x8*)(aX + s * 32);
            acc0 = __builtin_amdgcn_mfma_f32_16x16x32_bf16(a, b, acc0, 0, 0, 0);
        }
    }
    {
        int n = wn * 16 + lr;               // D: col = lane&15
        float bv = bias0[n];
        #pragma unroll
        for (int r = 0; r < 4; ++r) {       // D: row = (lane>>4)*4 + r
            int mloc = qr * 4 + r;
            float hv = tanhf(acc0[r] + bv);
            outh1[(size_t)(m0 + mloc) * 128 + n] = hv;
            hb[mloc * HSTR + n] = (__bf16)hv;
        }
    }
    __syncthreads();

    // ================= GEMM1: h2 = tanh([h1|h0_1] @ [Wih1|Whh1]^T + b) =================
    f32x4 acc1 = {};
    {
        const __bf16* aH = hb + lr * HSTR + qr * 8;
        #pragma unroll
        for (int s = 0; s < 8; ++s) {
            bf16x8 b = wp1[(size_t)(s * 8 + wn) * 64 + lane];
            bf16x8 a = *(const bf16x8*)(aH + s * 32);
            acc1 = __builtin_amdgcn_mfma_f32_16x16x32_bf16(a, b, acc1, 0, 0, 0);
        }
    }
    {
        int n = wn * 16 + lr;
        float bv = bias1[n];
        #pragma unroll
        for (int r = 0; r < 4; ++r) {
            int mloc = qr * 4 + r;
            float hv = tanhf(acc1[r] + bv);
            outh2[(size_t)(m0 + mloc) * 128 + n] = hv;
            h2b[mloc * H2STR + n] = (__bf16)hv;
        }
    }
    __syncthreads();

    // ================= heads: [cls|act] = h2 @ [Wcls|Wact]^T + b (N padded to 16) ======
    if (wn == 0) {
        f32x4 acc2 = {};
        const __bf16* aH2 = h2b + lr * H2STR + qr * 8;
        #pragma unroll
        for (int s = 0; s < 4; ++s) {
            bf16x8 a = *(const bf16x8*)(aH2 + s * 32);
            bf16x8 b = wph[(size_t)s * 64 + lane];
            acc2 = __builtin_amdgcn_mfma_f32_16x16x32_bf16(a, b, acc2, 0, 0, 0);
        }
        int n = lr;
        float bh = biash[n];
        #pragma unroll
        for (int r = 0; r < 4; ++r) {
            int mg = m0 + qr * 4 + r;
            float v = acc2[r] + bh;
            if (n < 10)      out[(size_t)mg * 10 + n] = v;
            else if (n < 12) out[(size_t)B_TOT * 10 + (size_t)mg * 2 + (n - 10)] = v;
        }
    }
}

extern "C" void kernel_launch(void* const* d_in, const int* in_sizes, int n_in,
                              void* d_out, int out_size, void* d_ws, size_t ws_size,
                              hipStream_t stream) {
    const float* image = (const float*)d_in[0];
    const int*   center = (const int*)d_in[1];
    const float* h0   = (const float*)d_in[2];
    const float* Wih0 = (const float*)d_in[3];
    const float* bih0 = (const float*)d_in[4];
    const float* Whh0 = (const float*)d_in[5];
    const float* bhh0 = (const float*)d_in[6];
    const float* Wih1 = (const float*)d_in[7];
    const float* bih1 = (const float*)d_in[8];
    const float* Whh1 = (const float*)d_in[9];
    const float* bhh1 = (const float*)d_in[10];
    const float* Wcls = (const float*)d_in[11];
    const float* bcls = (const float*)d_in[12];
    const float* Wact = (const float*)d_in[13];
    const float* bact = (const float*)d_in[14];

    prepack_kernel<<<53, 256, 0, stream>>>(Wih0, Whh0, Wih1, Whh1, Wcls, Wact,
                                           bih0, bhh0, bih1, bhh1, bcls, bact,
                                           (char*)d_ws);
    mnist_rnn_main<<<B_TOT / MTILE, 512, 0, stream>>>(
        image, center, h0, (const char*)d_ws, (float*)d_out);
}

// Round 4
// 41.231 us; speedup vs baseline: 1.1405x; 1.0140x over previous
//
#include <hip/hip_runtime.h>
#include <hip/hip_bf16.h>

#define B_TOT 16384
#define MTILE 16

typedef __bf16 bf16x8 __attribute__((ext_vector_type(8)));
typedef __bf16 bf16x4 __attribute__((ext_vector_type(4)));
typedef float  f32x4  __attribute__((ext_vector_type(4)));

// ---- workspace layout (bytes) ----
#define NG0 (17*8*64)
#define NG1 (8*8*64)
#define NGH (4*64)
#define WP0_OFF  0
#define WP1_OFF  (NG0*16)
#define WPH_OFF  (WP1_OFF + NG1*16)
#define BIAS0_OFF (WPH_OFF + NGH*16)
#define BIAS1_OFF (BIAS0_OFF + 512)
#define BIASH_OFF (BIAS1_OFF + 512)

__global__ __launch_bounds__(256) void prepack_kernel(
    const float* __restrict__ Wih0, const float* __restrict__ Whh0,
    const float* __restrict__ Wih1, const float* __restrict__ Whh1,
    const float* __restrict__ Wcls, const float* __restrict__ Wact,
    const float* __restrict__ bih0, const float* __restrict__ bhh0,
    const float* __restrict__ bih1, const float* __restrict__ bhh1,
    const float* __restrict__ bcls, const float* __restrict__ bact,
    char* __restrict__ ws)
{
    int idx = blockIdx.x * 256 + threadIdx.x;
    __bf16* wp0 = (__bf16*)(ws + WP0_OFF);
    __bf16* wp1 = (__bf16*)(ws + WP1_OFF);
    __bf16* wph = (__bf16*)(ws + WPH_OFF);
    float* bias0 = (float*)(ws + BIAS0_OFF);
    float* bias1 = (float*)(ws + BIAS1_OFF);
    float* biash = (float*)(ws + BIASH_OFF);

    if (idx < NG0) {
        int lane = idx & 63, g = idx >> 6, s = g >> 3, nb = g & 7;
        int n = nb * 16 + (lane & 15);
        int kb = s * 32 + (lane >> 4) * 8;
        bf16x8 v;
        #pragma unroll
        for (int j = 0; j < 8; ++j) {
            int k = kb + j;
            float x = 0.f;
            if (k < 400)      x = Wih0[n * 400 + k];
            else if (k < 528) x = Whh0[n * 128 + (k - 400)];
            v[j] = (__bf16)x;
        }
        *(bf16x8*)(wp0 + (size_t)idx * 8) = v;
    } else if (idx < NG0 + NG1) {
        int i2 = idx - NG0;
        int lane = i2 & 63, g = i2 >> 6, s = g >> 3, nb = g & 7;
        int n = nb * 16 + (lane & 15);
        int kb = s * 32 + (lane >> 4) * 8;
        bf16x8 v;
        #pragma unroll
        for (int j = 0; j < 8; ++j) {
            int k = kb + j;
            float x = (k < 128) ? Wih1[n * 128 + k] : Whh1[n * 128 + (k - 128)];
            v[j] = (__bf16)x;
        }
        *(bf16x8*)(wp1 + (size_t)i2 * 8) = v;
    } else if (idx < NG0 + NG1 + NGH) {
        int i3 = idx - NG0 - NG1;
        int lane = i3 & 63, s = i3 >> 6;
        int n = lane & 15;
        int kb = s * 32 + (lane >> 4) * 8;
        bf16x8 v;
        #pragma unroll
        for (int j = 0; j < 8; ++j) {
            int k = kb + j;
            float x = 0.f;
            if (n < 10)      x = Wcls[n * 128 + k];
            else if (n < 12) x = Wact[(n - 10) * 128 + k];
            v[j] = (__bf16)x;
        }
        *(bf16x8*)(wph + (size_t)i3 * 8) = v;
    } else {
        int i4 = idx - NG0 - NG1 - NGH;
        if (i4 < 128) bias0[i4] = bih0[i4] + bhh0[i4];
        else if (i4 < 256) { int i = i4 - 128; bias1[i] = bih1[i] + bhh1[i]; }
        else if (i4 < 272) {
            int i = i4 - 256;
            biash[i] = (i < 10) ? bcls[i] : ((i < 12) ? bact[i - 10] : 0.f);
        }
    }
}

// LDS layout (bf16 elems), MTILE=16:
//   xl  [16][552]  : crop X (0..399) | h0[0] (400..527) | zero pad (528..551)
//   hb  [16][264]  : h1 (0..127) | h0[1] (128..255)
//   h2b [16][136]  : h2 (aliases xl, used after xl dead)
#define XSTR 552
#define HSTR 264
#define H2STR 136

__device__ __forceinline__ float fast_tanh(float x) {
    // tanh(x) = 1 - 2/(exp2(x*2*log2e)+1), clamped to avoid inf/inf
    float cx = fminf(fmaxf(x, -9.f), 9.f);
    float t = __builtin_amdgcn_exp2f(cx * 2.8853900817779268f);
    return 1.f - 2.f * __builtin_amdgcn_rcpf(t + 1.f);
}

__global__ __launch_bounds__(512, 4) void mnist_rnn_main(
    const float* __restrict__ image, const int* __restrict__ center,
    const float* __restrict__ h0, const char* __restrict__ ws,
    float* __restrict__ out)
{
    const bf16x8* wp0 = (const bf16x8*)(ws + WP0_OFF);
    const bf16x8* wp1 = (const bf16x8*)(ws + WP1_OFF);
    const bf16x8* wph = (const bf16x8*)(ws + WPH_OFF);
    const float* bias0 = (const float*)(ws + BIAS0_OFF);
    const float* bias1 = (const float*)(ws + BIAS1_OFF);
    const float* biash = (const float*)(ws + BIASH_OFF);

    __shared__ __align__(16) __bf16 smem[MTILE * XSTR + MTILE * HSTR];
    __bf16* xl  = smem;                 // [16][552]
    __bf16* hb  = smem + MTILE * XSTR;  // [16][264]
    __bf16* h2b = smem;                 // [16][136] alias of xl

    const int t  = threadIdx.x;
    const int m0 = blockIdx.x * MTILE;
    const int lane = t & 63;
    const int wn = t >> 6;              // wave id; also N-slice: cols wn*16..wn*16+15
    const int qr = lane >> 4, lr = lane & 15;

    // ================= phase 0: issue ALL independent global loads =================
    // crop gather: wave wn owns samples mA=2*wn, mB=2*wn+1. The 20-row window of a
    // sample is a CONTIGUOUS range of its image; load it coalesced (2 rows x 28
    // lanes per iteration), 10 predicated iterations fully unrolled.
    const int mA = 2 * wn, mB = 2 * wn + 1;
    const int lr28 = lane / 28;         // 0,1 active; 2 -> idle lanes 56..63
    const int lx28 = lane - lr28 * 28;

    const int cxA = center[(m0 + mA) * 2 + 0];
    const int cyA = center[(m0 + mA) * 2 + 1];
    const int cxB = center[(m0 + mB) * 2 + 0];
    const int cyB = center[(m0 + mB) * 2 + 1];

    const int rloA = max(0, cyA - 20), rhiA = min(28, cyA);
    const int rloB = max(0, cyB - 20), rhiB = min(28, cyB);
    const float* imgA = image + (size_t)(m0 + mA) * 784;
    const float* imgB = image + (size_t)(m0 + mB) * 784;

    float gA[10], gB[10];
    #pragma unroll
    for (int it = 0; it < 10; ++it) {
        int iy = rloA + lr28 + it * 2;
        gA[it] = (lr28 < 2 && iy < rhiA) ? imgA[iy * 28 + lx28] : 0.f;
    }
    #pragma unroll
    for (int it = 0; it < 10; ++it) {
        int iy = rloB + lr28 + it * 2;
        gB[it] = (lr28 < 2 && iy < rhiB) ? imgB[iy * 28 + lx28] : 0.f;
    }

    // h0 loads (coalesced float4)
    const int hm = t >> 5, hk4 = (t & 31) * 4;
    const float4 v0 = *(const float4*)(h0 + (size_t)(m0 + hm) * 128 + hk4);
    const float4 v1 = *(const float4*)(h0 + (size_t)B_TOT * 128 + (size_t)(m0 + hm) * 128 + hk4);

    // preload ALL GEMM0 B-fragments (68 VGPRs) — consumed after the barrier
    bf16x8 bf[17];
    #pragma unroll
    for (int s = 0; s < 17; ++s) bf[s] = wp0[(size_t)(s * 8 + wn) * 64 + lane];

    // ================= phase 1: LDS staging =================
    // zero the crop region of our wave's 2 samples (so OOB stays 0)
    {
        unsigned int* z0 = (unsigned int*)(xl + mA * XSTR);
        unsigned int* z1 = (unsigned int*)(xl + mB * XSTR);
        #pragma unroll
        for (int i = 0; i < 4; ++i) {
            int idx = lane + i * 64;
            if (idx < 200) { z0[idx] = 0u; z1[idx] = 0u; }
        }
    }
    // zero K-pad cols 528..551
    if (t < 192) {
        int m = t / 12, c = (t - m * 12) * 2;
        *(unsigned int*)(xl + m * XSTR + 528 + c) = 0u;
    }
    // scatter crop into LDS
    #pragma unroll
    for (int it = 0; it < 10; ++it) {
        int iy = rloA + lr28 + it * 2;
        int r = iy - (cyA - 20), c = lx28 - (cxA - 20);
        if (lr28 < 2 && iy < rhiA && (unsigned)c < 20u)
            xl[mA * XSTR + r * 20 + c] = (__bf16)gA[it];
    }
    #pragma unroll
    for (int it = 0; it < 10; ++it) {
        int iy = rloB + lr28 + it * 2;
        int r = iy - (cyB - 20), c = lx28 - (cxB - 20);
        if (lr28 < 2 && iy < rhiB && (unsigned)c < 20u)
            xl[mB * XSTR + r * 20 + c] = (__bf16)gB[it];
    }
    // stage h0 to LDS
    {
        bf16x4 b0, b1;
        b0[0] = (__bf16)v0.x; b0[1] = (__bf16)v0.y; b0[2] = (__bf16)v0.z; b0[3] = (__bf16)v0.w;
        b1[0] = (__bf16)v1.x; b1[1] = (__bf16)v1.y; b1[2] = (__bf16)v1.z; b1[3] = (__bf16)v1.w;
        *(bf16x4*)(xl + hm * XSTR + 400 + hk4) = b0;
        *(bf16x4*)(hb + hm * HSTR + 128 + hk4) = b1;
    }
    __syncthreads();

    float* outh1 = out + (size_t)B_TOT * 12;
    float* outh2 = out + (size_t)B_TOT * 140;

    // ================= GEMM0: pure LDS + MFMA (B-frags already in regs) ============
    f32x4 acc0 = {};
    {
        const __bf16* aX = xl + lr * XSTR + qr * 8;
        #pragma unroll
        for (int s = 0; s < 17; ++s) {
            bf16x8 a = *(const bf16x8*)(aX + s * 32);
            acc0 = __builtin_amdgcn_mfma_f32_16x16x32_bf16(a, bf[s], acc0, 0, 0, 0);
        }
    }
    // preload GEMM1 B-fragments while GEMM0 epilogue runs
    bf16x8 bg[8];
    #pragma unroll
    for (int s = 0; s < 8; ++s) bg[s] = wp1[(size_t)(s * 8 + wn) * 64 + lane];

    {
        int n = wn * 16 + lr;               // D: col = lane&15
        float bv = bias0[n];
        #pragma unroll
        for (int r = 0; r < 4; ++r) {       // D: row = (lane>>4)*4 + r
            int mloc = qr * 4 + r;
            float hv = fast_tanh(acc0[r] + bv);
            outh1[(size_t)(m0 + mloc) * 128 + n] = hv;
            hb[mloc * HSTR + n] = (__bf16)hv;
        }
    }
    __syncthreads();

    // ================= GEMM1 =================
    f32x4 acc1 = {};
    {
        const __bf16* aH = hb + lr * HSTR + qr * 8;
        #pragma unroll
        for (int s = 0; s < 8; ++s) {
            bf16x8 a = *(const bf16x8*)(aH + s * 32);
            acc1 = __builtin_amdgcn_mfma_f32_16x16x32_bf16(a, bg[s], acc1, 0, 0, 0);
        }
    }
    // preload head B-fragments (wave 0 only needs them)
    bf16x8 bh[4];
    if (wn == 0) {
        #pragma unroll
        for (int s = 0; s < 4; ++s) bh[s] = wph[(size_t)s * 64 + lane];
    }
    {
        int n = wn * 16 + lr;
        float bv = bias1[n];
        #pragma unroll
        for (int r = 0; r < 4; ++r) {
            int mloc = qr * 4 + r;
            float hv = fast_tanh(acc1[r] + bv);
            outh2[(size_t)(m0 + mloc) * 128 + n] = hv;
            h2b[mloc * H2STR + n] = (__bf16)hv;
        }
    }
    __syncthreads();

    // ================= heads (wave 0): N padded to 16 =================
    if (wn == 0) {
        f32x4 acc2 = {};
        const __bf16* aH2 = h2b + lr * H2STR + qr * 8;
        #pragma unroll
        for (int s = 0; s < 4; ++s) {
            bf16x8 a = *(const bf16x8*)(aH2 + s * 32);
            acc2 = __builtin_amdgcn_mfma_f32_16x16x32_bf16(a, bh[s], acc2, 0, 0, 0);
        }
        int n = lr;
        float bhd = biash[n];
        #pragma unroll
        for (int r = 0; r < 4; ++r) {
            int mg = m0 + qr * 4 + r;
            float v = acc2[r] + bhd;
            if (n < 10)      out[(size_t)mg * 10 + n] = v;
            else if (n < 12) out[(size_t)B_TOT * 10 + (size_t)mg * 2 + (n - 10)] = v;
        }
    }
}

extern "C" void kernel_launch(void* const* d_in, const int* in_sizes, int n_in,
                              void* d_out, int out_size, void* d_ws, size_t ws_size,
                              hipStream_t stream) {
    const float* image = (const float*)d_in[0];
    const int*   center = (const int*)d_in[1];
    const float* h0   = (const float*)d_in[2];
    const float* Wih0 = (const float*)d_in[3];
    const float* bih0 = (const float*)d_in[4];
    const float* Whh0 = (const float*)d_in[5];
    const float* bhh0 = (const float*)d_in[6];
    const float* Wih1 = (const float*)d_in[7];
    const float* bih1 = (const float*)d_in[8];
    const float* Whh1 = (const float*)d_in[9];
    const float* bhh1 = (const float*)d_in[10];
    const float* Wcls = (const float*)d_in[11];
    const float* bcls = (const float*)d_in[12];
    const float* Wact = (const float*)d_in[13];
    const float* bact = (const float*)d_in[14];

    prepack_kernel<<<53, 256, 0, stream>>>(Wih0, Whh0, Wih1, Whh1, Wcls, Wact,
                                           bih0, bhh0, bih1, bhh1, bcls, bact,
                                           (char*)d_ws);
    mnist_rnn_main<<<B_TOT / MTILE, 512, 0, stream>>>(
        image, center, h0, (const char*)d_ws, (float*)d_out);
}